// Round 3
// baseline (2059.357 us; speedup 1.0000x reference)
//
#include <hip/hip_runtime.h>

#define TT 4000   // timesteps
#define HH 64     // hidden
#define NB 256    // batch
#define EE 128    // fc out

typedef __attribute__((ext_vector_type(2))) _Float16 h2;
typedef __attribute__((ext_vector_type(8))) _Float16 h8;

__device__ __forceinline__ float ftanh(float x) {
    return fmaf(2.f, __builtin_amdgcn_rcpf(1.f + __expf(-2.f * x)), -1.f);
}

#if __has_builtin(__builtin_amdgcn_fdot2)
#define FDOT2(a, b, c) __builtin_amdgcn_fdot2((a), (b), (c), false)
#else
#define FDOT2(a, b, c) fmaf((float)(a).x, (float)(b).x, fmaf((float)(a).y, (float)(b).y, (c)))
#endif

// h2 sub-extract from h8 register (sub-register addressing, no memory).
#define H2V(V, i) (__builtin_shufflevector((V), (V), 2 * (i), 2 * (i) + 1))

// DPP helpers (VALU pipe, no LDS). ctrl must be an ICE -> template param.
template <int CTRL>
__device__ __forceinline__ float dpp_mov(float v) {
    return __int_as_float(__builtin_amdgcn_update_dpp(
        0, __float_as_int(v), CTRL, 0xF, 0xF, true));
}
#define DPP_XOR1 0xB1   // quad_perm [1,0,3,2]  (flip s)      [HW-verified R8/R9]
#define DPP_XOR2 0x4E   // quad_perm [2,3,0,1]  (flip u)      [HW-verified R8/R9]
#define DPP_FB   0x44   // quad_perm [0,1,0,1]  (broadcast u=0 per s)
#define DPP_OB   0xEE   // quad_perm [2,3,2,3]  (broadcast u=1 per s)
#define DPP_SHR4 0x114  // row_shr:4            (p=0 quad -> p=1 quad) [R13-verified]

#define CVT2(d0, d1, s) h2 d0 = h2{(_Float16)(s).x, (_Float16)(s).y}, \
                           d1 = h2{(_Float16)(s).z, (_Float16)(s).w};

// 4 dot2-accumulates of one h8 slice into acc.
#define D4(acc, W0, W1, W2, W3, Hv) \
    acc = FDOT2(W0, H2V(Hv, 0), acc); \
    acc = FDOT2(W1, H2V(Hv, 1), acc); \
    acc = FDOT2(W2, H2V(Hv, 2), acc); \
    acc = FDOT2(W3, H2V(Hv, 3), acc);

// R16: dependence-chain split. Evidence: R14 (halve DS instr/CU) = -92 cyc,
// R15 (halve b128/lane, +32 dpp) = +63 cyc == exactly the dpp issue cost ->
// LDS reads are pipelined ~free. Step = issue(~330) + chain stalls. The
// 32-deep serial fdot2 chains (acc1a/acc1b: B0..B15 then C0..C15) are the
// only structure big enough to hide ~500 cyc of stall: if v_dot2 latency is
// ~16 cyc, a 32-chain with 4-way ILP stalls 8 cyc per link. Fix: 12 chains
// of 8 fdot2 (acc0*: 2x8, acc1*: 4x8), merged by 8 adds -> 24 issue-cycles
// between dependent ops. h-read reverted to R14 broadcast b128 (R15's
// quad-read regressed).
//
// lane = 16*rowgrp + 8*nn + 4*p + 2*u + s ; na = w*8 + rowgrp*2 + nn (0..31),
// nb = na+32 ; gate = p + 2u (p=0 quad: i,i,g,g ; p=1 quad: f,f,o,o),
// s = k-half AND layer assignment.
//
// Layer pipelining (verified R3-R10): iter t computes L0 gates(t) from
// h0(t-1) and L1 gates(t-1) from {h1(t-2), h0(t-1)}; s=0 lanes run the L0
// act/cell path, s=1 the L1 path. 1 barrier/step, h fp16 double-buffered.
__global__ __launch_bounds__(256, 1)
void lstm2_fc_kernel(const float* __restrict__ x,      // [B, T, 1]
                     const float* __restrict__ W_ih0,  // [256, 1]
                     const float* __restrict__ W_hh0,  // [256, 64]
                     const float* __restrict__ b_ih0,  // [256]
                     const float* __restrict__ b_hh0,  // [256]
                     const float* __restrict__ W_ih1,  // [256, 64]
                     const float* __restrict__ W_hh1,  // [256, 64]
                     const float* __restrict__ b_ih1,  // [256]
                     const float* __restrict__ b_hh1,  // [256]
                     const float* __restrict__ W_fc,   // [128, 64]
                     const float* __restrict__ b_fc,   // [128]
                     float* __restrict__ out)          // [B, 128]
{
    const int b    = blockIdx.x;
    const int tid  = threadIdx.x;     // 0..255
    const int w    = tid >> 6;        // wave 0..3
    const int lane = tid & 63;
    const int ss   = lane & 1;        // k-half AND layer assignment
    const int uu   = (lane >> 1) & 1;
    const int pp   = (lane >> 2) & 1;
    const int nn   = (lane >> 3) & 1;
    const int na   = w * 8 + (lane >> 4) * 2 + nn;   // h-index 0..31
    const int nb   = na + 32;                        // h-index 32..63
    const int gidx = pp + 2 * uu;                    // 0:i 1:f 2:g 3:o

    __shared__ float x_s[TT];                          // 16 KB
    __shared__ __align__(16) _Float16 hbuf[2][2 * HH]; // [parity][h0|h1], fp16

    for (int t = tid; t < TT; t += 256) x_s[t] = x[(size_t)b * TT + t];
    if (tid < 4 * HH) ((_Float16*)hbuf)[tid] = (_Float16)0.f;

    const int rowa = gidx * HH + na;   // gate row in [0,256)
    const int rowb = gidx * HH + nb;   // = rowa + 32
    // --- Named-scalar weight load: 6 thirty-two-wide slices -> 96 h2 ---
    const float4* p0 = (const float4*)(W_hh0 + rowa * HH + ss * 32);
    const float4* p1 = (const float4*)(W_ih1 + rowa * HH + ss * 32);
    const float4* p2 = (const float4*)(W_hh1 + rowa * HH + ss * 32);
    const float4* p3 = (const float4*)(W_hh0 + rowb * HH + ss * 32);
    const float4* p4 = (const float4*)(W_ih1 + rowb * HH + ss * 32);
    const float4* p5 = (const float4*)(W_hh1 + rowb * HH + ss * 32);
    float4 qa0 = p0[0], qa1 = p0[1], qa2 = p0[2], qa3 = p0[3];
    float4 qa4 = p0[4], qa5 = p0[5], qa6 = p0[6], qa7 = p0[7];
    float4 qb0 = p1[0], qb1 = p1[1], qb2 = p1[2], qb3 = p1[3];
    float4 qb4 = p1[4], qb5 = p1[5], qb6 = p1[6], qb7 = p1[7];
    float4 qc0 = p2[0], qc1 = p2[1], qc2 = p2[2], qc3 = p2[3];
    float4 qc4 = p2[4], qc5 = p2[5], qc6 = p2[6], qc7 = p2[7];
    float4 qd0 = p3[0], qd1 = p3[1], qd2 = p3[2], qd3 = p3[3];
    float4 qd4 = p3[4], qd5 = p3[5], qd6 = p3[6], qd7 = p3[7];
    float4 qe0 = p4[0], qe1 = p4[1], qe2 = p4[2], qe3 = p4[3];
    float4 qe4 = p4[4], qe5 = p4[5], qe6 = p4[6], qe7 = p4[7];
    float4 qf0 = p5[0], qf1 = p5[1], qf2 = p5[2], qf3 = p5[3];
    float4 qf4 = p5[4], qf5 = p5[5], qf6 = p5[6], qf7 = p5[7];
    CVT2(A0,  A1,  qa0) CVT2(A2,  A3,  qa1) CVT2(A4,  A5,  qa2) CVT2(A6,  A7,  qa3)
    CVT2(A8,  A9,  qa4) CVT2(A10, A11, qa5) CVT2(A12, A13, qa6) CVT2(A14, A15, qa7)
    CVT2(B0,  B1,  qb0) CVT2(B2,  B3,  qb1) CVT2(B4,  B5,  qb2) CVT2(B6,  B7,  qb3)
    CVT2(B8,  B9,  qb4) CVT2(B10, B11, qb5) CVT2(B12, B13, qb6) CVT2(B14, B15, qb7)
    CVT2(C0,  C1,  qc0) CVT2(C2,  C3,  qc1) CVT2(C4,  C5,  qc2) CVT2(C6,  C7,  qc3)
    CVT2(C8,  C9,  qc4) CVT2(C10, C11, qc5) CVT2(C12, C13, qc6) CVT2(C14, C15, qc7)
    CVT2(D0,  D1,  qd0) CVT2(D2,  D3,  qd1) CVT2(D4,  D5,  qd2) CVT2(D6,  D7,  qd3)
    CVT2(D8,  D9,  qd4) CVT2(D10, D11, qd5) CVT2(D12, D13, qd6) CVT2(D14, D15, qd7)
    CVT2(E0,  E1,  qe0) CVT2(E2,  E3,  qe1) CVT2(E4,  E5,  qe2) CVT2(E6,  E7,  qe3)
    CVT2(E8,  E9,  qe4) CVT2(E10, E11, qe5) CVT2(E12, E13, qe6) CVT2(E14, E15, qe7)
    CVT2(F0,  F1,  qf0) CVT2(F2,  F3,  qf1) CVT2(F4,  F5,  qf2) CVT2(F6,  F7,  qf3)
    CVT2(F8,  F9,  qf4) CVT2(F10, F11, qf5) CVT2(F12, F13, qf6) CVT2(F14, F15, qf7)

    float wxa  = W_ih0[rowa];
    float wxb  = W_ih0[rowb];
    float bb0a = b_ih0[rowa] + b_hh0[rowa];
    float bb0b = b_ih0[rowb] + b_hh0[rowb];
    float bb1a = b_ih1[rowa] + b_hh1[rowa];
    float bb1b = b_ih1[rowb] + b_hh1[rowb];

    // Remat fences (R7/R9-proven). <=24 operands each (inline-asm limit margin).
    asm volatile("" : "+v"(A0), "+v"(A1), "+v"(A2),  "+v"(A3),
                      "+v"(A4), "+v"(A5), "+v"(A6),  "+v"(A7),
                      "+v"(A8), "+v"(A9), "+v"(A10), "+v"(A11),
                      "+v"(A12),"+v"(A13),"+v"(A14), "+v"(A15),
                      "+v"(B0), "+v"(B1), "+v"(B2),  "+v"(B3),
                      "+v"(B4), "+v"(B5), "+v"(B6),  "+v"(B7));
    asm volatile("" : "+v"(B8), "+v"(B9), "+v"(B10), "+v"(B11),
                      "+v"(B12),"+v"(B13),"+v"(B14), "+v"(B15),
                      "+v"(C0), "+v"(C1), "+v"(C2),  "+v"(C3),
                      "+v"(C4), "+v"(C5), "+v"(C6),  "+v"(C7),
                      "+v"(C8), "+v"(C9), "+v"(C10), "+v"(C11),
                      "+v"(C12),"+v"(C13),"+v"(C14), "+v"(C15));
    asm volatile("" : "+v"(D0), "+v"(D1), "+v"(D2),  "+v"(D3),
                      "+v"(D4), "+v"(D5), "+v"(D6),  "+v"(D7),
                      "+v"(D8), "+v"(D9), "+v"(D10), "+v"(D11),
                      "+v"(D12),"+v"(D13),"+v"(D14), "+v"(D15),
                      "+v"(E0), "+v"(E1), "+v"(E2),  "+v"(E3),
                      "+v"(E4), "+v"(E5), "+v"(E6),  "+v"(E7));
    asm volatile("" : "+v"(E8), "+v"(E9), "+v"(E10), "+v"(E11),
                      "+v"(E12),"+v"(E13),"+v"(E14), "+v"(E15),
                      "+v"(F0), "+v"(F1), "+v"(F2),  "+v"(F3),
                      "+v"(F4), "+v"(F5), "+v"(F6),  "+v"(F7),
                      "+v"(F8), "+v"(F9), "+v"(F10), "+v"(F11),
                      "+v"(F12),"+v"(F13),"+v"(F14), "+v"(F15));
    asm volatile("" : "+v"(wxa), "+v"(wxb), "+v"(bb0a),
                      "+v"(bb0b),"+v"(bb1a),"+v"(bb1b));

    // act(z) = mm * rcp(1 + exp(kk*z)) + aa ; tanh only for gate g (gidx==2).
    const bool isg = (gidx == 2);
    const float kk = isg ? -2.f : -1.f;
    const float mm = isg ?  2.f :  1.f;
    const float aa = isg ? -1.f :  0.f;

    const bool wlane = (pp == 1) && (uu == 0);   // h writers (f lanes)
    const int  hoffa = ss * HH + na;             // s=0 -> h0[n], s=1 -> h1[n]
    const int  hoffb = ss * HH + nb;
    float cca = 0.f, ccb = 0.f;                  // valid in p=1 lanes

    __syncthreads();

    for (int t = 0; t <= TT; ++t) {
        const float xt = x_s[(t < TT) ? t : 0];
        const h8* hb = (const h8*)hbuf[t & 1];
        // This lane's 32-half k-slices, SHARED by both n-paths (8 b128/lane).
        h8 Ha = hb[4 * ss + 0], Hc = hb[4 * ss + 1];
        h8 He = hb[4 * ss + 2], Hg = hb[4 * ss + 3];
        h8 Ga = hb[8 + 4 * ss + 0], Gc = hb[8 + 4 * ss + 1];
        h8 Ge = hb[8 + 4 * ss + 2], Gg = hb[8 + 4 * ss + 3];

        // 12 independent 8-deep chains (latency-hiding: 24 issue-cyc between
        // dependent fdot2), merged by 8 adds below.
        float s00a = ss ? 0.f : fmaf(xt, wxa, bb0a);   // A0..A7
        float s01a = 0.f;                              // A8..A15
        float s10a = ss ? 0.f : bb1a;                  // B0..B7
        float s11a = 0.f;                              // B8..B15
        float s12a = 0.f;                              // C0..C7
        float s13a = 0.f;                              // C8..C15
        float s00b = ss ? 0.f : fmaf(xt, wxb, bb0b);   // D0..D7
        float s01b = 0.f;                              // D8..D15
        float s10b = ss ? 0.f : bb1b;                  // E0..E7
        float s11b = 0.f;                              // E8..E15
        float s12b = 0.f;                              // F0..F7
        float s13b = 0.f;                              // F8..F15

        D4(s00a, A0,  A1,  A2,  A3,  Ha)  D4(s00b, D0,  D1,  D2,  D3,  Ha)
        D4(s10a, B0,  B1,  B2,  B3,  Ha)  D4(s10b, E0,  E1,  E2,  E3,  Ha)
        D4(s12a, C0,  C1,  C2,  C3,  Ga)  D4(s12b, F0,  F1,  F2,  F3,  Ga)
        D4(s00a, A4,  A5,  A6,  A7,  Hc)  D4(s00b, D4,  D5,  D6,  D7,  Hc)
        D4(s10a, B4,  B5,  B6,  B7,  Hc)  D4(s10b, E4,  E5,  E6,  E7,  Hc)
        D4(s12a, C4,  C5,  C6,  C7,  Gc)  D4(s12b, F4,  F5,  F6,  F7,  Gc)
        D4(s01a, A8,  A9,  A10, A11, He)  D4(s01b, D8,  D9,  D10, D11, He)
        D4(s11a, B8,  B9,  B10, B11, He)  D4(s11b, E8,  E9,  E10, E11, He)
        D4(s13a, C8,  C9,  C10, C11, Ge)  D4(s13b, F8,  F9,  F10, F11, Ge)
        D4(s01a, A12, A13, A14, A15, Hg)  D4(s01b, D12, D13, D14, D15, Hg)
        D4(s11a, B12, B13, B14, B15, Hg)  D4(s11b, E12, E13, E14, E15, Hg)
        D4(s13a, C12, C13, C14, C15, Gg)  D4(s13b, F12, F13, F14, F15, Gg)

        float acc0a = s00a + s01a;
        float acc0b = s00b + s01b;
        float acc1a = (s10a + s11a) + (s12a + s13a);
        float acc1b = (s10b + s11b) + (s12b + s13b);

        // s-butterfly (DPP xor1): both s-lanes hold full row sums.
        acc0a += dpp_mov<DPP_XOR1>(acc0a);
        acc0b += dpp_mov<DPP_XOR1>(acc0b);
        acc1a += dpp_mov<DPP_XOR1>(acc1a);
        acc1b += dpp_mov<DPP_XOR1>(acc1b);

        // Per-lane layer: s=0 -> L0(t), s=1 -> L1(t-1). One activation per n.
        float za  = ss ? acc1a : acc0a;
        float zb  = ss ? acc1b : acc0b;
        float eza = __expf(kk * za);
        float ezb = __expf(kk * zb);
        float va  = fmaf(mm, __builtin_amdgcn_rcpf(1.f + eza), aa);
        float vb  = fmaf(mm, __builtin_amdgcn_rcpf(1.f + ezb), aa);

        // Gate combine, all DPP (independent per n-path):
        //  p=0 quad (i,i,g,g): ig = val * xor2(val)     [per s]
        //  row_shr:4 hands ig to the p=1 quad (f,f,o,o) [dest i <- src i-4]
        //  f/o broadcast per s via quad_perm 0x44/0xEE
        float igqa = va * dpp_mov<DPP_XOR2>(va);
        float igqb = vb * dpp_mov<DPP_XOR2>(vb);
        float iga  = dpp_mov<DPP_SHR4>(igqa);
        float igb  = dpp_mov<DPP_SHR4>(igqb);
        float fba  = dpp_mov<DPP_FB>(va);
        float fbb  = dpp_mov<DPP_FB>(vb);
        float oba  = dpp_mov<DPP_OB>(va);
        float obb  = dpp_mov<DPP_OB>(vb);

        float cna = fmaf(fba, cca, iga);
        float cnb = fmaf(fbb, ccb, igb);
        float hna = oba * ftanh(cna);
        float hnb = obb * ftanh(cnb);
        bool ok = ss ? (t > 0) : (t < TT);       // L1 skip at 0, L0 at TT
        cca = ok ? cna : cca;
        ccb = ok ? cnb : ccb;
        if (wlane && ok) {
            _Float16* hw = hbuf[(t + 1) & 1];
            hw[hoffa] = (_Float16)hna;
            hw[hoffb] = (_Float16)hnb;
        }

        __syncthreads();                         // h exchange (double-buffered)
    }

    // FC on final h1 = h1(TT-1), in hbuf[(TT+1)&1][64..128).
    if (tid < EE) {
        const _Float16* h1f = &hbuf[(TT + 1) & 1][HH];
        float acc = b_fc[tid];
        const float4* wf = (const float4*)(W_fc + tid * HH);
        #pragma unroll
        for (int k = 0; k < HH / 4; ++k) {
            float4 v = wf[k];
            acc = fmaf(v.x, (float)h1f[4*k+0], acc);
            acc = fmaf(v.y, (float)h1f[4*k+1], acc);
            acc = fmaf(v.z, (float)h1f[4*k+2], acc);
            acc = fmaf(v.w, (float)h1f[4*k+3], acc);
        }
        out[(size_t)b * EE + tid] = acc;
    }
}

extern "C" void kernel_launch(void* const* d_in, const int* in_sizes, int n_in,
                              void* d_out, int out_size, void* d_ws, size_t ws_size,
                              hipStream_t stream) {
    const float* x     = (const float*)d_in[0];
    const float* W_ih0 = (const float*)d_in[1];
    const float* W_hh0 = (const float*)d_in[2];
    const float* b_ih0 = (const float*)d_in[3];
    const float* b_hh0 = (const float*)d_in[4];
    const float* W_ih1 = (const float*)d_in[5];
    const float* W_hh1 = (const float*)d_in[6];
    const float* b_ih1 = (const float*)d_in[7];
    const float* b_hh1 = (const float*)d_in[8];
    const float* W_fc  = (const float*)d_in[9];
    const float* b_fc  = (const float*)d_in[10];
    float* out = (float*)d_out;

    lstm2_fc_kernel<<<dim3(NB), dim3(256), 0, stream>>>(
        x, W_ih0, W_hh0, b_ih0, b_hh0, W_ih1, W_hh1, b_ih1, b_hh1, W_fc, b_fc, out);
}

// Round 4
// 1811.236 us; speedup vs baseline: 1.1370x; 1.1370x over previous
//
#include <hip/hip_runtime.h>

#define TT 4000   // timesteps
#define HH 64     // hidden
#define NB 256    // batch
#define EE 128    // fc out

typedef __attribute__((ext_vector_type(2))) _Float16 h2;
typedef __attribute__((ext_vector_type(8))) _Float16 h8;

__device__ __forceinline__ float ftanh(float x) {
    return fmaf(2.f, __builtin_amdgcn_rcpf(1.f + __expf(-2.f * x)), -1.f);
}

#if __has_builtin(__builtin_amdgcn_fdot2)
#define FDOT2(a, b, c) __builtin_amdgcn_fdot2((a), (b), (c), false)
#else
#define FDOT2(a, b, c) fmaf((float)(a).x, (float)(b).x, fmaf((float)(a).y, (float)(b).y, (c)))
#endif

// h2 sub-extract from h8 register (sub-register addressing, no memory).
#define H2V(V, i) (__builtin_shufflevector((V), (V), 2 * (i), 2 * (i) + 1))

// DPP helpers (VALU pipe, no LDS). ctrl must be an ICE -> template param.
template <int CTRL>
__device__ __forceinline__ float dpp_mov(float v) {
    return __int_as_float(__builtin_amdgcn_update_dpp(
        0, __float_as_int(v), CTRL, 0xF, 0xF, true));
}
#define DPP_XOR1 0xB1   // quad_perm [1,0,3,2]  (flip s)      [HW-verified R8/R9]
#define DPP_XOR2 0x4E   // quad_perm [2,3,0,1]  (flip u)      [HW-verified R8/R9]
#define DPP_FB   0x44   // quad_perm [0,1,0,1]  (broadcast u=0 per s)
#define DPP_OB   0xEE   // quad_perm [2,3,2,3]  (broadcast u=1 per s)
#define DPP_SHR4 0x114  // row_shr:4            (p=0 quad -> p=1 quad) [R13-verified]

#define CVT2(d0, d1, s) h2 d0 = h2{(_Float16)(s).x, (_Float16)(s).y}, \
                           d1 = h2{(_Float16)(s).z, (_Float16)(s).w};

// R17: instruction-level round-robin dot interleave. R16's failure isolated
// the true stall: the D4 macro emitted 4 CONSECUTIVE dependent fdot2 on one
// accumulator; in-order issue pays full fdot2 latency (L~8) per link ->
// ~600 cyc of stall/step that chain-COUNT changes can't touch (R16 kept the
// D4 grouping -> null). Evidence: R15's +62cyc == exact issue cost of its
// added DPPs (marginal instrs cost issue, not stall). Fix: six 16-link
// chains (A,D,B,E,C,F), ONE fdot2 from each per row -> same-acc dependents
// spaced 6 instrs = 12 issue-cyc >= L -> dot section ~issue-bound (~192cyc).
// ds_reads reordered (Ha,Ga,Hc,Gc,...) to match consumption. Merge = 2 adds.
// Rest is R14 (1907us) verbatim: broadcast b128 h-read (R15 quad-read
// regressed), 256 thr, 2 n per lane.
//
// lane = 16*rowgrp + 8*nn + 4*p + 2*u + s ; na = w*8 + rowgrp*2 + nn (0..31),
// nb = na+32 ; gate = p + 2u (p=0 quad: i,i,g,g ; p=1 quad: f,f,o,o),
// s = k-half AND layer assignment.
//
// Layer pipelining (verified R3-R10): iter t computes L0 gates(t) from
// h0(t-1) and L1 gates(t-1) from {h1(t-2), h0(t-1)}; s=0 lanes run the L0
// act/cell path, s=1 the L1 path. 1 barrier/step, h fp16 double-buffered.
__global__ __launch_bounds__(256, 1)
void lstm2_fc_kernel(const float* __restrict__ x,      // [B, T, 1]
                     const float* __restrict__ W_ih0,  // [256, 1]
                     const float* __restrict__ W_hh0,  // [256, 64]
                     const float* __restrict__ b_ih0,  // [256]
                     const float* __restrict__ b_hh0,  // [256]
                     const float* __restrict__ W_ih1,  // [256, 64]
                     const float* __restrict__ W_hh1,  // [256, 64]
                     const float* __restrict__ b_ih1,  // [256]
                     const float* __restrict__ b_hh1,  // [256]
                     const float* __restrict__ W_fc,   // [128, 64]
                     const float* __restrict__ b_fc,   // [128]
                     float* __restrict__ out)          // [B, 128]
{
    const int b    = blockIdx.x;
    const int tid  = threadIdx.x;     // 0..255
    const int w    = tid >> 6;        // wave 0..3
    const int lane = tid & 63;
    const int ss   = lane & 1;        // k-half AND layer assignment
    const int uu   = (lane >> 1) & 1;
    const int pp   = (lane >> 2) & 1;
    const int nn   = (lane >> 3) & 1;
    const int na   = w * 8 + (lane >> 4) * 2 + nn;   // h-index 0..31
    const int nb   = na + 32;                        // h-index 32..63
    const int gidx = pp + 2 * uu;                    // 0:i 1:f 2:g 3:o

    __shared__ float x_s[TT];                          // 16 KB
    __shared__ __align__(16) _Float16 hbuf[2][2 * HH]; // [parity][h0|h1], fp16

    for (int t = tid; t < TT; t += 256) x_s[t] = x[(size_t)b * TT + t];
    if (tid < 4 * HH) ((_Float16*)hbuf)[tid] = (_Float16)0.f;

    const int rowa = gidx * HH + na;   // gate row in [0,256)
    const int rowb = gidx * HH + nb;   // = rowa + 32
    // --- Named-scalar weight load: 6 thirty-two-wide slices -> 96 h2 ---
    const float4* p0 = (const float4*)(W_hh0 + rowa * HH + ss * 32);
    const float4* p1 = (const float4*)(W_ih1 + rowa * HH + ss * 32);
    const float4* p2 = (const float4*)(W_hh1 + rowa * HH + ss * 32);
    const float4* p3 = (const float4*)(W_hh0 + rowb * HH + ss * 32);
    const float4* p4 = (const float4*)(W_ih1 + rowb * HH + ss * 32);
    const float4* p5 = (const float4*)(W_hh1 + rowb * HH + ss * 32);
    float4 qa0 = p0[0], qa1 = p0[1], qa2 = p0[2], qa3 = p0[3];
    float4 qa4 = p0[4], qa5 = p0[5], qa6 = p0[6], qa7 = p0[7];
    float4 qb0 = p1[0], qb1 = p1[1], qb2 = p1[2], qb3 = p1[3];
    float4 qb4 = p1[4], qb5 = p1[5], qb6 = p1[6], qb7 = p1[7];
    float4 qc0 = p2[0], qc1 = p2[1], qc2 = p2[2], qc3 = p2[3];
    float4 qc4 = p2[4], qc5 = p2[5], qc6 = p2[6], qc7 = p2[7];
    float4 qd0 = p3[0], qd1 = p3[1], qd2 = p3[2], qd3 = p3[3];
    float4 qd4 = p3[4], qd5 = p3[5], qd6 = p3[6], qd7 = p3[7];
    float4 qe0 = p4[0], qe1 = p4[1], qe2 = p4[2], qe3 = p4[3];
    float4 qe4 = p4[4], qe5 = p4[5], qe6 = p4[6], qe7 = p4[7];
    float4 qf0 = p5[0], qf1 = p5[1], qf2 = p5[2], qf3 = p5[3];
    float4 qf4 = p5[4], qf5 = p5[5], qf6 = p5[6], qf7 = p5[7];
    CVT2(A0,  A1,  qa0) CVT2(A2,  A3,  qa1) CVT2(A4,  A5,  qa2) CVT2(A6,  A7,  qa3)
    CVT2(A8,  A9,  qa4) CVT2(A10, A11, qa5) CVT2(A12, A13, qa6) CVT2(A14, A15, qa7)
    CVT2(B0,  B1,  qb0) CVT2(B2,  B3,  qb1) CVT2(B4,  B5,  qb2) CVT2(B6,  B7,  qb3)
    CVT2(B8,  B9,  qb4) CVT2(B10, B11, qb5) CVT2(B12, B13, qb6) CVT2(B14, B15, qb7)
    CVT2(C0,  C1,  qc0) CVT2(C2,  C3,  qc1) CVT2(C4,  C5,  qc2) CVT2(C6,  C7,  qc3)
    CVT2(C8,  C9,  qc4) CVT2(C10, C11, qc5) CVT2(C12, C13, qc6) CVT2(C14, C15, qc7)
    CVT2(D0,  D1,  qd0) CVT2(D2,  D3,  qd1) CVT2(D4,  D5,  qd2) CVT2(D6,  D7,  qd3)
    CVT2(D8,  D9,  qd4) CVT2(D10, D11, qd5) CVT2(D12, D13, qd6) CVT2(D14, D15, qd7)
    CVT2(E0,  E1,  qe0) CVT2(E2,  E3,  qe1) CVT2(E4,  E5,  qe2) CVT2(E6,  E7,  qe3)
    CVT2(E8,  E9,  qe4) CVT2(E10, E11, qe5) CVT2(E12, E13, qe6) CVT2(E14, E15, qe7)
    CVT2(F0,  F1,  qf0) CVT2(F2,  F3,  qf1) CVT2(F4,  F5,  qf2) CVT2(F6,  F7,  qf3)
    CVT2(F8,  F9,  qf4) CVT2(F10, F11, qf5) CVT2(F12, F13, qf6) CVT2(F14, F15, qf7)

    float wxa  = W_ih0[rowa];
    float wxb  = W_ih0[rowb];
    float bb0a = b_ih0[rowa] + b_hh0[rowa];
    float bb0b = b_ih0[rowb] + b_hh0[rowb];
    float bb1a = b_ih1[rowa] + b_hh1[rowa];
    float bb1b = b_ih1[rowb] + b_hh1[rowb];

    // Remat fences (R7/R9-proven). <=24 operands each (inline-asm limit margin).
    asm volatile("" : "+v"(A0), "+v"(A1), "+v"(A2),  "+v"(A3),
                      "+v"(A4), "+v"(A5), "+v"(A6),  "+v"(A7),
                      "+v"(A8), "+v"(A9), "+v"(A10), "+v"(A11),
                      "+v"(A12),"+v"(A13),"+v"(A14), "+v"(A15),
                      "+v"(B0), "+v"(B1), "+v"(B2),  "+v"(B3),
                      "+v"(B4), "+v"(B5), "+v"(B6),  "+v"(B7));
    asm volatile("" : "+v"(B8), "+v"(B9), "+v"(B10), "+v"(B11),
                      "+v"(B12),"+v"(B13),"+v"(B14), "+v"(B15),
                      "+v"(C0), "+v"(C1), "+v"(C2),  "+v"(C3),
                      "+v"(C4), "+v"(C5), "+v"(C6),  "+v"(C7),
                      "+v"(C8), "+v"(C9), "+v"(C10), "+v"(C11),
                      "+v"(C12),"+v"(C13),"+v"(C14), "+v"(C15));
    asm volatile("" : "+v"(D0), "+v"(D1), "+v"(D2),  "+v"(D3),
                      "+v"(D4), "+v"(D5), "+v"(D6),  "+v"(D7),
                      "+v"(D8), "+v"(D9), "+v"(D10), "+v"(D11),
                      "+v"(D12),"+v"(D13),"+v"(D14), "+v"(D15),
                      "+v"(E0), "+v"(E1), "+v"(E2),  "+v"(E3),
                      "+v"(E4), "+v"(E5), "+v"(E6),  "+v"(E7));
    asm volatile("" : "+v"(E8), "+v"(E9), "+v"(E10), "+v"(E11),
                      "+v"(E12),"+v"(E13),"+v"(E14), "+v"(E15),
                      "+v"(F0), "+v"(F1), "+v"(F2),  "+v"(F3),
                      "+v"(F4), "+v"(F5), "+v"(F6),  "+v"(F7),
                      "+v"(F8), "+v"(F9), "+v"(F10), "+v"(F11),
                      "+v"(F12),"+v"(F13),"+v"(F14), "+v"(F15));
    asm volatile("" : "+v"(wxa), "+v"(wxb), "+v"(bb0a),
                      "+v"(bb0b),"+v"(bb1a),"+v"(bb1b));

    // act(z) = mm * rcp(1 + exp(kk*z)) + aa ; tanh only for gate g (gidx==2).
    const bool isg = (gidx == 2);
    const float kk = isg ? -2.f : -1.f;
    const float mm = isg ?  2.f :  1.f;
    const float aa = isg ? -1.f :  0.f;

    const bool wlane = (pp == 1) && (uu == 0);   // h writers (f lanes)
    const int  hoffa = ss * HH + na;             // s=0 -> h0[n], s=1 -> h1[n]
    const int  hoffb = ss * HH + nb;
    float cca = 0.f, ccb = 0.f;                  // valid in p=1 lanes

    __syncthreads();

    // One fdot2 from each of the 6 chains; same-acc dependents spaced 6
    // instrs (12 issue-cyc) -> no latency stall on in-order issue.
    #define ROW(Aj, Dj, Bj, Ej, Cj, Fj, Hv, Gv, e) \
        s0a = FDOT2(Aj, H2V(Hv, e), s0a); \
        s0b = FDOT2(Dj, H2V(Hv, e), s0b); \
        s1a = FDOT2(Bj, H2V(Hv, e), s1a); \
        s1b = FDOT2(Ej, H2V(Hv, e), s1b); \
        s2a = FDOT2(Cj, H2V(Gv, e), s2a); \
        s2b = FDOT2(Fj, H2V(Gv, e), s2b);

    for (int t = 0; t <= TT; ++t) {
        const float xt = x_s[(t < TT) ? t : 0];
        const h8* hb = (const h8*)hbuf[t & 1];
        // 8 b128 broadcast reads, ordered to match consumption (H,G pairs).
        h8 Ha = hb[4 * ss + 0], Ga = hb[8 + 4 * ss + 0];
        h8 Hc = hb[4 * ss + 1], Gc = hb[8 + 4 * ss + 1];
        h8 He = hb[4 * ss + 2], Ge = hb[8 + 4 * ss + 2];
        h8 Hg = hb[4 * ss + 3], Gg = hb[8 + 4 * ss + 3];

        // 6 chains, 16 links each.
        float s0a = ss ? 0.f : fmaf(xt, wxa, bb0a);   // A: L0(a)
        float s0b = ss ? 0.f : fmaf(xt, wxb, bb0b);   // D: L0(b)
        float s1a = ss ? 0.f : bb1a;                  // B: L1(a) h0-part
        float s1b = ss ? 0.f : bb1b;                  // E: L1(b) h0-part
        float s2a = 0.f;                              // C: L1(a) h1-part
        float s2b = 0.f;                              // F: L1(b) h1-part

        ROW(A0,  D0,  B0,  E0,  C0,  F0,  Ha, Ga, 0)
        ROW(A1,  D1,  B1,  E1,  C1,  F1,  Ha, Ga, 1)
        ROW(A2,  D2,  B2,  E2,  C2,  F2,  Ha, Ga, 2)
        ROW(A3,  D3,  B3,  E3,  C3,  F3,  Ha, Ga, 3)
        ROW(A4,  D4,  B4,  E4,  C4,  F4,  Hc, Gc, 0)
        ROW(A5,  D5,  B5,  E5,  C5,  F5,  Hc, Gc, 1)
        ROW(A6,  D6,  B6,  E6,  C6,  F6,  Hc, Gc, 2)
        ROW(A7,  D7,  B7,  E7,  C7,  F7,  Hc, Gc, 3)
        ROW(A8,  D8,  B8,  E8,  C8,  F8,  He, Ge, 0)
        ROW(A9,  D9,  B9,  E9,  C9,  F9,  He, Ge, 1)
        ROW(A10, D10, B10, E10, C10, F10, He, Ge, 2)
        ROW(A11, D11, B11, E11, C11, F11, He, Ge, 3)
        ROW(A12, D12, B12, E12, C12, F12, Hg, Gg, 0)
        ROW(A13, D13, B13, E13, C13, F13, Hg, Gg, 1)
        ROW(A14, D14, B14, E14, C14, F14, Hg, Gg, 2)
        ROW(A15, D15, B15, E15, C15, F15, Hg, Gg, 3)

        float acc0a = s0a;
        float acc0b = s0b;
        float acc1a = s1a + s2a;
        float acc1b = s1b + s2b;

        // s-butterfly (DPP xor1): both s-lanes hold full row sums.
        acc0a += dpp_mov<DPP_XOR1>(acc0a);
        acc0b += dpp_mov<DPP_XOR1>(acc0b);
        acc1a += dpp_mov<DPP_XOR1>(acc1a);
        acc1b += dpp_mov<DPP_XOR1>(acc1b);

        // Per-lane layer: s=0 -> L0(t), s=1 -> L1(t-1). One activation per n.
        float za  = ss ? acc1a : acc0a;
        float zb  = ss ? acc1b : acc0b;
        float eza = __expf(kk * za);
        float ezb = __expf(kk * zb);
        float va  = fmaf(mm, __builtin_amdgcn_rcpf(1.f + eza), aa);
        float vb  = fmaf(mm, __builtin_amdgcn_rcpf(1.f + ezb), aa);

        // Gate combine, all DPP (independent per n-path):
        //  p=0 quad (i,i,g,g): ig = val * xor2(val)     [per s]
        //  row_shr:4 hands ig to the p=1 quad (f,f,o,o) [dest i <- src i-4]
        //  f/o broadcast per s via quad_perm 0x44/0xEE
        float igqa = va * dpp_mov<DPP_XOR2>(va);
        float igqb = vb * dpp_mov<DPP_XOR2>(vb);
        float iga  = dpp_mov<DPP_SHR4>(igqa);
        float igb  = dpp_mov<DPP_SHR4>(igqb);
        float fba  = dpp_mov<DPP_FB>(va);
        float fbb  = dpp_mov<DPP_FB>(vb);
        float oba  = dpp_mov<DPP_OB>(va);
        float obb  = dpp_mov<DPP_OB>(vb);

        float cna = fmaf(fba, cca, iga);
        float cnb = fmaf(fbb, ccb, igb);
        float hna = oba * ftanh(cna);
        float hnb = obb * ftanh(cnb);
        bool ok = ss ? (t > 0) : (t < TT);       // L1 skip at 0, L0 at TT
        cca = ok ? cna : cca;
        ccb = ok ? cnb : ccb;
        if (wlane && ok) {
            _Float16* hw = hbuf[(t + 1) & 1];
            hw[hoffa] = (_Float16)hna;
            hw[hoffb] = (_Float16)hnb;
        }

        __syncthreads();                         // h exchange (double-buffered)
    }
    #undef ROW

    // FC on final h1 = h1(TT-1), in hbuf[(TT+1)&1][64..128).
    if (tid < EE) {
        const _Float16* h1f = &hbuf[(TT + 1) & 1][HH];
        float acc = b_fc[tid];
        const float4* wf = (const float4*)(W_fc + tid * HH);
        #pragma unroll
        for (int k = 0; k < HH / 4; ++k) {
            float4 v = wf[k];
            acc = fmaf(v.x, (float)h1f[4*k+0], acc);
            acc = fmaf(v.y, (float)h1f[4*k+1], acc);
            acc = fmaf(v.z, (float)h1f[4*k+2], acc);
            acc = fmaf(v.w, (float)h1f[4*k+3], acc);
        }
        out[(size_t)b * EE + tid] = acc;
    }
}

extern "C" void kernel_launch(void* const* d_in, const int* in_sizes, int n_in,
                              void* d_out, int out_size, void* d_ws, size_t ws_size,
                              hipStream_t stream) {
    const float* x     = (const float*)d_in[0];
    const float* W_ih0 = (const float*)d_in[1];
    const float* W_hh0 = (const float*)d_in[2];
    const float* b_ih0 = (const float*)d_in[3];
    const float* b_hh0 = (const float*)d_in[4];
    const float* W_ih1 = (const float*)d_in[5];
    const float* W_hh1 = (const float*)d_in[6];
    const float* b_ih1 = (const float*)d_in[7];
    const float* b_hh1 = (const float*)d_in[8];
    const float* W_fc  = (const float*)d_in[9];
    const float* b_fc  = (const float*)d_in[10];
    float* out = (float*)d_out;

    lstm2_fc_kernel<<<dim3(NB), dim3(256), 0, stream>>>(
        x, W_ih0, W_hh0, b_ih0, b_hh0, W_ih1, W_hh1, b_ih1, b_hh1, W_fc, b_fc, out);
}